// Round 13
// baseline (256.561 us; speedup 1.0000x reference)
//
#include <hip/hip_runtime.h>
#include <hip/hip_fp16.h>

#define BN_EPS 1e-5f
#define SLOT 12288

typedef _Float16 half2_t __attribute__((ext_vector_type(2)));
typedef _Float16 half8_t __attribute__((ext_vector_type(8)));

static __device__ __forceinline__ float fdot2(half2_t a, half2_t b, float c) {
    return __builtin_amdgcn_fdot2(a, b, c, false);
}

// ================= bucketed CSR build (fixed-slot, no pre-count) =================

__global__ void k_init(int* __restrict__ bcur, int B) {
    int i = threadIdx.x;
    if (i < B) bcur[i] = i * SLOT;
}

// payload u32 = src | ((dst&255) << 16)
__global__ void k_bscatter(const int* __restrict__ src, const int* __restrict__ dst,
                           int* bcur, unsigned int* __restrict__ ebuf, int E, int B) {
    __shared__ int cnt[256];
    __shared__ int gb[256];
    int tid = threadIdx.x;
    cnt[tid] = 0;
    __syncthreads();
    int e0 = blockIdx.x * 2048;
    int bk[8], rk[8];
    unsigned int pay[8];
#pragma unroll
    for (int j = 0; j < 8; ++j) {
        int e = e0 + j * 256 + tid;
        if (e < E) {
            int d = dst[e];
            int b = d >> 8;
            bk[j] = b;
            rk[j] = atomicAdd(&cnt[b], 1);
            pay[j] = (unsigned int)src[e] | ((unsigned int)(d & 255) << 16);
        } else {
            bk[j] = -1; rk[j] = 0; pay[j] = 0;
        }
    }
    __syncthreads();
    if (tid < B && cnt[tid] > 0) gb[tid] = atomicAdd(&bcur[tid], cnt[tid]);
    __syncthreads();
#pragma unroll
    for (int j = 0; j < 8; ++j)
        if (bk[j] >= 0) ebuf[gb[bk[j]] + rk[j]] = pay[j];
}

// per-bucket: hist -> scan -> row_ptr/len/dinv -> fine scatter into col slot
__global__ void k_bfinal(const unsigned int* __restrict__ ebuf, const int* __restrict__ bcur,
                         int* __restrict__ row_ptr, unsigned short* __restrict__ len,
                         float* __restrict__ dinv, unsigned short* __restrict__ col, int N) {
    __shared__ int cnt[256];
    __shared__ int sc[256];
    __shared__ int cur[256];
    int tid = threadIdx.x;
    int b = blockIdx.x;
    int node0 = b << 8;
    int ebeg = b * SLOT, eend = bcur[b];

    cnt[tid] = 0;
    __syncthreads();
    for (int i = ebeg + tid; i < eend; i += 256)
        atomicAdd(&cnt[ebuf[i] >> 16], 1);
    __syncthreads();
    int myc = cnt[tid];
    sc[tid] = myc;
    __syncthreads();
    for (int off = 1; off < 256; off <<= 1) {
        int t = (tid >= off) ? sc[tid - off] : 0;
        __syncthreads();
        sc[tid] += t;
        __syncthreads();
    }
    int excl = sc[tid] - myc;
    cur[tid] = ebeg + excl;
    int node = node0 + tid;
    if (node < N) {
        row_ptr[node] = ebeg + excl;
        len[node] = (unsigned short)myc;
        dinv[node] = rsqrtf((float)(myc + 1));  // +1 self-loop
    }
    __syncthreads();
    for (int i = ebeg + tid; i < eend; i += 256) {
        unsigned int p = ebuf[i];
        int dl = p >> 16;
        int pos = atomicAdd(&cur[dl], 1);
        col[pos] = (unsigned short)(p & 0xFFFFu);
    }
}

// ================= GEMM (fp16 operands, fdot2, f32 accum) =================
// Output rows padded to 32 half2 (128B) so gathers are one aligned line per edge.
template <int K, int FOUT, bool FP16IN>
__launch_bounds__(256)
__global__ void k_gemm_scale(const void* __restrict__ Xv, const float* __restrict__ W,
                             const float* __restrict__ dinv, half2_t* __restrict__ HS, int N) {
    constexpr int KK = K / 2;
    constexpr int XSTR = (K == 128) ? 66 : 36;
    __shared__ half2_t xs2[64][XSTR];
    __shared__ half2_t wl2[KK][FOUT];
    int tid = threadIdx.x;
    int row0 = blockIdx.x * 64;

    if constexpr (FP16IN) {
        const _Float16* X = (const _Float16*)Xv;
        constexpr int U = 64 * K / 8;
        for (int u = tid; u < U; u += 256) {
            int row = u / (K / 8), q = u % (K / 8);
            int grow = row0 + row;
            uint4 v = make_uint4(0u, 0u, 0u, 0u);
            if (grow < N) v = *(const uint4*)&X[(size_t)grow * K + q * 8];
            *(uint4*)&xs2[row][q * 4] = v;
        }
    } else {
        const float* X = (const float*)Xv;
        constexpr int U = 64 * K / 4;
        for (int u = tid; u < U; u += 256) {
            int row = u / (K / 4), c = u % (K / 4);
            int grow = row0 + row;
            half2_t h0 = (half2_t)(_Float16)0, h1 = (half2_t)(_Float16)0;
            if (grow < N) {
                float4 v = *(const float4*)&X[(size_t)grow * K + c * 4];
                h0[0] = (_Float16)v.x; h0[1] = (_Float16)v.y;
                h1[0] = (_Float16)v.z; h1[1] = (_Float16)v.w;
            }
            xs2[row][2 * c] = h0;
            xs2[row][2 * c + 1] = h1;
        }
    }
    for (int i = tid; i < KK * FOUT; i += 256) {
        int kk = i / FOUT, f = i % FOUT;
        half2_t h;
        h[0] = (_Float16)W[(2 * kk) * FOUT + f];
        h[1] = (_Float16)W[(2 * kk + 1) * FOUT + f];
        wl2[kk][f] = h;
    }
    __syncthreads();

    int tc = tid & 15, tr = tid >> 4;
    if (4 * tc < FOUT) {
        float acc[4][4] = {};
#pragma unroll 4
        for (int kk = 0; kk < KK; ++kk) {
            half2_t a0 = xs2[4 * tr + 0][kk];
            half2_t a1 = xs2[4 * tr + 1][kk];
            half2_t a2 = xs2[4 * tr + 2][kk];
            half2_t a3 = xs2[4 * tr + 3][kk];
            half8_t wv = *(const half8_t*)&wl2[kk][4 * tc];
            half2_t w0 = {wv[0], wv[1]};
            half2_t w1 = {wv[2], wv[3]};
            half2_t w2 = {wv[4], wv[5]};
            half2_t w3 = {wv[6], wv[7]};
            acc[0][0] = fdot2(a0, w0, acc[0][0]); acc[0][1] = fdot2(a0, w1, acc[0][1]);
            acc[0][2] = fdot2(a0, w2, acc[0][2]); acc[0][3] = fdot2(a0, w3, acc[0][3]);
            acc[1][0] = fdot2(a1, w0, acc[1][0]); acc[1][1] = fdot2(a1, w1, acc[1][1]);
            acc[1][2] = fdot2(a1, w2, acc[1][2]); acc[1][3] = fdot2(a1, w3, acc[1][3]);
            acc[2][0] = fdot2(a2, w0, acc[2][0]); acc[2][1] = fdot2(a2, w1, acc[2][1]);
            acc[2][2] = fdot2(a2, w2, acc[2][2]); acc[2][3] = fdot2(a2, w3, acc[2][3]);
            acc[3][0] = fdot2(a3, w0, acc[3][0]); acc[3][1] = fdot2(a3, w1, acc[3][1]);
            acc[3][2] = fdot2(a3, w2, acc[3][2]); acc[3][3] = fdot2(a3, w3, acc[3][3]);
        }
#pragma unroll
        for (int i = 0; i < 4; ++i) {
            int row = row0 + 4 * tr + i;
            if (row < N) {
                float dv = dinv[row];
                half2_t p0, p1;
                p0[0] = (_Float16)(dv * acc[i][0]); p0[1] = (_Float16)(dv * acc[i][1]);
                p1[0] = (_Float16)(dv * acc[i][2]); p1[1] = (_Float16)(dv * acc[i][3]);
                HS[(size_t)row * 32 + 2 * tc] = p0;      // padded 128B rows
                HS[(size_t)row * 32 + 2 * tc + 1] = p1;
            }
        }
    }
}

// ================= Aggregation (wide-gather + fdot2 accumulate, 4-deep) =================
// wave per node; 8-lane groups; lane loads half8 (16B) of features [8s,8s+8).
// 32 edges in flight per wave (4 unroll). Accumulate via fdot2 with (1,0)/(0,1):
// 8 VALU insts per edge instead of 16 (cvt+add).
template <int FOUT, bool BN>
__launch_bounds__(256)
__global__ void k_agg(const half8_t* __restrict__ hs8, const unsigned short* __restrict__ col,
                      const int* __restrict__ row_ptr, const unsigned short* __restrict__ len,
                      const float* __restrict__ dinv, const float* __restrict__ b,
                      const float* __restrict__ g, const float* __restrict__ be,
                      const float* __restrict__ m, const float* __restrict__ v,
                      void* __restrict__ outv, int N) {
    constexpr int NS = FOUT / 8;  // valid half8 per row (8 for 64, 5 for 40)
    constexpr int NG = 8;
    int gtid = blockIdx.x * blockDim.x + threadIdx.x;
    int wave = gtid >> 6;
    int lane = gtid & 63;
    int g8 = lane >> 3;
    int s = lane & 7;
    int nwaves = (gridDim.x * blockDim.x) >> 6;
    bool act = s < NS;

    const half2_t ONE0 = {(_Float16)1.0f, (_Float16)0.0f};
    const half2_t ONE1 = {(_Float16)0.0f, (_Float16)1.0f};

    float bias[8], sf[8], tf[8];
    if (act) {
#pragma unroll
        for (int j = 0; j < 8; ++j) {
            int f = 8 * s + j;
            bias[j] = b[f];
            if (BN) {
                sf[j] = g[f] * rsqrtf(v[f] + BN_EPS);
                tf[j] = be[f] - m[f] * sf[j];
            }
        }
    }

    for (int node = wave; node < N; node += nwaves) {
        int beg = row_ptr[node];
        int end = beg + (int)len[node];
        float a0[8] = {}, a1[8] = {}, a2[8] = {}, a3[8] = {};
        if (act && g8 == 0) {
            half8_t t = hs8[(size_t)node * 8 + s];
#pragma unroll
            for (int j = 0; j < 8; ++j) a0[j] = (float)t[j];
        }

#define ACC(A, T)                                                        \
        {                                                                \
            half2_t p0 = {T[0], T[1]}, p1 = {T[2], T[3]};                \
            half2_t p2 = {T[4], T[5]}, p3 = {T[6], T[7]};                \
            A[0] = fdot2(p0, ONE0, A[0]); A[1] = fdot2(p0, ONE1, A[1]);  \
            A[2] = fdot2(p1, ONE0, A[2]); A[3] = fdot2(p1, ONE1, A[3]);  \
            A[4] = fdot2(p2, ONE0, A[4]); A[5] = fdot2(p2, ONE1, A[5]);  \
            A[6] = fdot2(p3, ONE0, A[6]); A[7] = fdot2(p3, ONE1, A[7]);  \
        }

        int e = beg + g8;
        for (; e + 3 * NG < end; e += 4 * NG) {
            int i0 = __builtin_nontemporal_load(&col[e]);
            int i1 = __builtin_nontemporal_load(&col[e + NG]);
            int i2 = __builtin_nontemporal_load(&col[e + 2 * NG]);
            int i3 = __builtin_nontemporal_load(&col[e + 3 * NG]);
            if (act) {
                half8_t t0 = hs8[(size_t)i0 * 8 + s];
                half8_t t1 = hs8[(size_t)i1 * 8 + s];
                half8_t t2 = hs8[(size_t)i2 * 8 + s];
                half8_t t3 = hs8[(size_t)i3 * 8 + s];
                ACC(a0, t0); ACC(a1, t1); ACC(a2, t2); ACC(a3, t3);
            }
        }
        for (; e < end; e += NG) {
            int i0 = __builtin_nontemporal_load(&col[e]);
            if (act) {
                half8_t t0 = hs8[(size_t)i0 * 8 + s];
                ACC(a0, t0);
            }
        }
#undef ACC

#pragma unroll
        for (int j = 0; j < 8; ++j) {
            float sj = (a0[j] + a1[j]) + (a2[j] + a3[j]);
            sj += __shfl_xor(sj, 8);
            sj += __shfl_xor(sj, 16);
            sj += __shfl_xor(sj, 32);
            a0[j] = sj;
        }
        if (g8 == 0 && act) {
            float dv = dinv[node];
            if (BN) {
                half8_t h;
#pragma unroll
                for (int j = 0; j < 8; ++j) {
                    float o = dv * a0[j] + bias[j];
                    o = fmaxf(o * sf[j] + tf[j], 0.0f);
                    h[j] = (_Float16)o;
                }
                ((half8_t*)outv)[(size_t)node * NS + s] = h;  // y compact N x 64
            } else {
                float o[8];
#pragma unroll
                for (int j = 0; j < 8; ++j) o[j] = dv * a0[j] + bias[j];
                float* op = (float*)outv + (size_t)node * FOUT + 8 * s;
                *(float4*)op = make_float4(o[0], o[1], o[2], o[3]);
                *(float4*)(op + 4) = make_float4(o[4], o[5], o[6], o[7]);
            }
        }
    }
}

// ================= launch =================

extern "C" void kernel_launch(void* const* d_in, const int* in_sizes, int n_in,
                              void* d_out, int out_size, void* d_ws, size_t ws_size,
                              hipStream_t stream) {
    const float* x   = (const float*)d_in[0];
    const int*   ei  = (const int*)d_in[1];
    const float* W1  = (const float*)d_in[2];
    const float* b1  = (const float*)d_in[3];
    const float* g1  = (const float*)d_in[4];
    const float* be1 = (const float*)d_in[5];
    const float* m1  = (const float*)d_in[6];
    const float* v1  = (const float*)d_in[7];
    const float* W2  = (const float*)d_in[8];
    const float* b2  = (const float*)d_in[9];
    const float* g2  = (const float*)d_in[10];
    const float* be2 = (const float*)d_in[11];
    const float* m2  = (const float*)d_in[12];
    const float* v2  = (const float*)d_in[13];
    const float* W3  = (const float*)d_in[14];
    const float* b3  = (const float*)d_in[15];

    const int FIN = 128, H = 64;
    int N = in_sizes[0] / FIN;       // 50000
    int E = in_sizes[1] / 2;         // 1600000
    const int* src = ei;
    const int* dst = ei + E;
    int B = (N + 255) >> 8;          // 196 buckets

    char* ws = (char*)d_ws;
    size_t off = 0;
    auto carve = [&](size_t bytes) -> void* {
        void* p = ws + off;
        off += (bytes + 255) & ~(size_t)255;
        return p;
    };
    float*  dinv    = (float*)carve((size_t)N * 4);
    int*    row_ptr = (int*)carve((size_t)N * 4);
    unsigned short* len = (unsigned short*)carve((size_t)N * 2);
    unsigned short* col = (unsigned short*)carve((size_t)B * SLOT * 2);
    unsigned int*   ebuf = (unsigned int*)carve((size_t)B * SLOT * 4);
    half2_t* hs     = (half2_t*)carve((size_t)N * 64 * 2);  // padded 128B rows
    _Float16* y     = (_Float16*)carve((size_t)N * 64 * 2);
    int*    bcur    = (int*)carve(512 * 4);
    (void)ws_size; (void)n_in; (void)out_size;

    int eb2k = (E + 2047) / 2048;

    k_init<<<1, 256, 0, stream>>>(bcur, B);
    k_bscatter<<<eb2k, 256, 0, stream>>>(src, dst, bcur, ebuf, E, B);
    k_bfinal<<<B, 256, 0, stream>>>(ebuf, bcur, row_ptr, len, dinv, col, N);

    int gb = (N + 63) / 64;
    const half8_t* hs8 = (const half8_t*)hs;
    // layer 1
    k_gemm_scale<128, 64, false><<<gb, 256, 0, stream>>>(x, W1, dinv, hs, N);
    k_agg<64, true><<<4096, 256, 0, stream>>>(hs8, col, row_ptr, len, dinv,
                                              b1, g1, be1, m1, v1, y, N);
    // layer 2
    k_gemm_scale<64, 64, true><<<gb, 256, 0, stream>>>(y, W2, dinv, hs, N);
    k_agg<64, true><<<4096, 256, 0, stream>>>(hs8, col, row_ptr, len, dinv,
                                              b2, g2, be2, m2, v2, y, N);
    // layer 3: 40 features in padded 128B rows
    k_gemm_scale<64, 40, true><<<gb, 256, 0, stream>>>(y, W3, dinv, hs, N);
    k_agg<40, false><<<4096, 256, 0, stream>>>(hs8, col, row_ptr, len, dinv,
                                               b3, nullptr, nullptr, nullptr, nullptr,
                                               d_out, N);
}

// Round 14
// 218.213 us; speedup vs baseline: 1.1757x; 1.1757x over previous
//
#include <hip/hip_runtime.h>
#include <hip/hip_fp16.h>

#define BN_EPS 1e-5f
#define SLOT 12288

typedef _Float16 half2_t __attribute__((ext_vector_type(2)));
typedef _Float16 half8_t __attribute__((ext_vector_type(8)));

static __device__ __forceinline__ float fdot2(half2_t a, half2_t b, float c) {
    return __builtin_amdgcn_fdot2(a, b, c, false);
}

// ================= bucketed CSR build (fixed-slot, no pre-count) =================

__global__ void k_init(int* __restrict__ bcur, int B) {
    int i = threadIdx.x;
    if (i < B) bcur[i] = i * SLOT;
}

// payload u32 = src | ((dst&255) << 16)
__global__ void k_bscatter(const int* __restrict__ src, const int* __restrict__ dst,
                           int* bcur, unsigned int* __restrict__ ebuf, int E, int B) {
    __shared__ int cnt[256];
    __shared__ int gb[256];
    int tid = threadIdx.x;
    cnt[tid] = 0;
    __syncthreads();
    int e0 = blockIdx.x * 2048;
    int bk[8], rk[8];
    unsigned int pay[8];
#pragma unroll
    for (int j = 0; j < 8; ++j) {
        int e = e0 + j * 256 + tid;
        if (e < E) {
            int d = dst[e];
            int b = d >> 8;
            bk[j] = b;
            rk[j] = atomicAdd(&cnt[b], 1);
            pay[j] = (unsigned int)src[e] | ((unsigned int)(d & 255) << 16);
        } else {
            bk[j] = -1; rk[j] = 0; pay[j] = 0;
        }
    }
    __syncthreads();
    if (tid < B && cnt[tid] > 0) gb[tid] = atomicAdd(&bcur[tid], cnt[tid]);
    __syncthreads();
#pragma unroll
    for (int j = 0; j < 8; ++j)
        if (bk[j] >= 0) ebuf[gb[bk[j]] + rk[j]] = pay[j];
}

// per-bucket: hist -> scan -> row_ptr/len/dinv -> fine scatter into col slot
__global__ void k_bfinal(const unsigned int* __restrict__ ebuf, const int* __restrict__ bcur,
                         int* __restrict__ row_ptr, unsigned short* __restrict__ len,
                         float* __restrict__ dinv, unsigned short* __restrict__ col, int N) {
    __shared__ int cnt[256];
    __shared__ int sc[256];
    __shared__ int cur[256];
    int tid = threadIdx.x;
    int b = blockIdx.x;
    int node0 = b << 8;
    int ebeg = b * SLOT, eend = bcur[b];

    cnt[tid] = 0;
    __syncthreads();
    for (int i = ebeg + tid; i < eend; i += 256)
        atomicAdd(&cnt[ebuf[i] >> 16], 1);
    __syncthreads();
    int myc = cnt[tid];
    sc[tid] = myc;
    __syncthreads();
    for (int off = 1; off < 256; off <<= 1) {
        int t = (tid >= off) ? sc[tid - off] : 0;
        __syncthreads();
        sc[tid] += t;
        __syncthreads();
    }
    int excl = sc[tid] - myc;
    cur[tid] = ebeg + excl;
    int node = node0 + tid;
    if (node < N) {
        row_ptr[node] = ebeg + excl;
        len[node] = (unsigned short)myc;
        dinv[node] = rsqrtf((float)(myc + 1));  // +1 self-loop
    }
    __syncthreads();
    for (int i = ebeg + tid; i < eend; i += 256) {
        unsigned int p = ebuf[i];
        int dl = p >> 16;
        int pos = atomicAdd(&cur[dl], 1);
        col[pos] = (unsigned short)(p & 0xFFFFu);
    }
}

// ================= GEMM (fp16 operands, fdot2, f32 accum) =================
// Output rows padded to 32 half2 (128B) so gathers are one aligned line per edge.
template <int K, int FOUT, bool FP16IN>
__launch_bounds__(256)
__global__ void k_gemm_scale(const void* __restrict__ Xv, const float* __restrict__ W,
                             const float* __restrict__ dinv, half2_t* __restrict__ HS, int N) {
    constexpr int KK = K / 2;
    constexpr int XSTR = (K == 128) ? 66 : 36;
    __shared__ half2_t xs2[64][XSTR];
    __shared__ half2_t wl2[KK][FOUT];
    int tid = threadIdx.x;
    int row0 = blockIdx.x * 64;

    if constexpr (FP16IN) {
        const _Float16* X = (const _Float16*)Xv;
        constexpr int U = 64 * K / 8;
        for (int u = tid; u < U; u += 256) {
            int row = u / (K / 8), q = u % (K / 8);
            int grow = row0 + row;
            uint4 v = make_uint4(0u, 0u, 0u, 0u);
            if (grow < N) v = *(const uint4*)&X[(size_t)grow * K + q * 8];
            *(uint4*)&xs2[row][q * 4] = v;
        }
    } else {
        const float* X = (const float*)Xv;
        constexpr int U = 64 * K / 4;
        for (int u = tid; u < U; u += 256) {
            int row = u / (K / 4), c = u % (K / 4);
            int grow = row0 + row;
            half2_t h0 = (half2_t)(_Float16)0, h1 = (half2_t)(_Float16)0;
            if (grow < N) {
                float4 v = *(const float4*)&X[(size_t)grow * K + c * 4];
                h0[0] = (_Float16)v.x; h0[1] = (_Float16)v.y;
                h1[0] = (_Float16)v.z; h1[1] = (_Float16)v.w;
            }
            xs2[row][2 * c] = h0;
            xs2[row][2 * c + 1] = h1;
        }
    }
    for (int i = tid; i < KK * FOUT; i += 256) {
        int kk = i / FOUT, f = i % FOUT;
        half2_t h;
        h[0] = (_Float16)W[(2 * kk) * FOUT + f];
        h[1] = (_Float16)W[(2 * kk + 1) * FOUT + f];
        wl2[kk][f] = h;
    }
    __syncthreads();

    int tc = tid & 15, tr = tid >> 4;
    if (4 * tc < FOUT) {
        float acc[4][4] = {};
#pragma unroll 4
        for (int kk = 0; kk < KK; ++kk) {
            half2_t a0 = xs2[4 * tr + 0][kk];
            half2_t a1 = xs2[4 * tr + 1][kk];
            half2_t a2 = xs2[4 * tr + 2][kk];
            half2_t a3 = xs2[4 * tr + 3][kk];
            half8_t wv = *(const half8_t*)&wl2[kk][4 * tc];
            half2_t w0 = {wv[0], wv[1]};
            half2_t w1 = {wv[2], wv[3]};
            half2_t w2 = {wv[4], wv[5]};
            half2_t w3 = {wv[6], wv[7]};
            acc[0][0] = fdot2(a0, w0, acc[0][0]); acc[0][1] = fdot2(a0, w1, acc[0][1]);
            acc[0][2] = fdot2(a0, w2, acc[0][2]); acc[0][3] = fdot2(a0, w3, acc[0][3]);
            acc[1][0] = fdot2(a1, w0, acc[1][0]); acc[1][1] = fdot2(a1, w1, acc[1][1]);
            acc[1][2] = fdot2(a1, w2, acc[1][2]); acc[1][3] = fdot2(a1, w3, acc[1][3]);
            acc[2][0] = fdot2(a2, w0, acc[2][0]); acc[2][1] = fdot2(a2, w1, acc[2][1]);
            acc[2][2] = fdot2(a2, w2, acc[2][2]); acc[2][3] = fdot2(a2, w3, acc[2][3]);
            acc[3][0] = fdot2(a3, w0, acc[3][0]); acc[3][1] = fdot2(a3, w1, acc[3][1]);
            acc[3][2] = fdot2(a3, w2, acc[3][2]); acc[3][3] = fdot2(a3, w3, acc[3][3]);
        }
#pragma unroll
        for (int i = 0; i < 4; ++i) {
            int row = row0 + 4 * tr + i;
            if (row < N) {
                float dv = dinv[row];
                half2_t p0, p1;
                p0[0] = (_Float16)(dv * acc[i][0]); p0[1] = (_Float16)(dv * acc[i][1]);
                p1[0] = (_Float16)(dv * acc[i][2]); p1[1] = (_Float16)(dv * acc[i][3]);
                HS[(size_t)row * 32 + 2 * tc] = p0;      // padded 128B rows
                HS[(size_t)row * 32 + 2 * tc + 1] = p1;
            }
        }
    }
}

// ================= Aggregation (wide-gather, cvt+add, 32-bit addressing) =================
// wave per node; 8-lane groups; lane loads half8 (16B) of features [8s,8s+8).
// 16 edges in flight per wave (2 unroll). Gather address = base + i0*128 (int).
template <int FOUT, bool BN>
__launch_bounds__(256)
__global__ void k_agg(const half8_t* __restrict__ hs8, const unsigned short* __restrict__ col,
                      const int* __restrict__ row_ptr, const unsigned short* __restrict__ len,
                      const float* __restrict__ dinv, const float* __restrict__ b,
                      const float* __restrict__ g, const float* __restrict__ be,
                      const float* __restrict__ m, const float* __restrict__ v,
                      void* __restrict__ outv, int N) {
    constexpr int NS = FOUT / 8;  // valid half8 per row (8 for 64, 5 for 40)
    constexpr int NG = 8;
    int gtid = blockIdx.x * blockDim.x + threadIdx.x;
    int wave = gtid >> 6;
    int lane = gtid & 63;
    int g8 = lane >> 3;
    int s = lane & 7;
    int nwaves = (gridDim.x * blockDim.x) >> 6;
    bool act = s < NS;

    const char* hbase = (const char*)hs8 + s * 16;  // per-lane sub-row base

    float bias[8], sf[8], tf[8];
    if (act) {
#pragma unroll
        for (int j = 0; j < 8; ++j) {
            int f = 8 * s + j;
            bias[j] = b[f];
            if (BN) {
                sf[j] = g[f] * rsqrtf(v[f] + BN_EPS);
                tf[j] = be[f] - m[f] * sf[j];
            }
        }
    }

    for (int node = wave; node < N; node += nwaves) {
        int beg = row_ptr[node];
        int end = beg + (int)len[node];
        float acc0[8] = {}, acc1[8] = {};
        if (act && g8 == 0) {
            half8_t t = *(const half8_t*)(hbase + node * 128);
#pragma unroll
            for (int j = 0; j < 8; ++j) acc0[j] = (float)t[j];
        }
        int e = beg + g8;
        for (; e + NG < end; e += 2 * NG) {
            int i0 = (int)__builtin_nontemporal_load(&col[e]);
            int i1 = (int)__builtin_nontemporal_load(&col[e + NG]);
            if (act) {
                half8_t t0 = *(const half8_t*)(hbase + i0 * 128);
                half8_t t1 = *(const half8_t*)(hbase + i1 * 128);
#pragma unroll
                for (int j = 0; j < 8; ++j) { acc0[j] += (float)t0[j]; acc1[j] += (float)t1[j]; }
            }
        }
        if (e < end) {
            int i0 = (int)__builtin_nontemporal_load(&col[e]);
            if (act) {
                half8_t t0 = *(const half8_t*)(hbase + i0 * 128);
#pragma unroll
                for (int j = 0; j < 8; ++j) acc0[j] += (float)t0[j];
            }
        }
#pragma unroll
        for (int j = 0; j < 8; ++j) {
            float sj = acc0[j] + acc1[j];
            sj += __shfl_xor(sj, 8);
            sj += __shfl_xor(sj, 16);
            sj += __shfl_xor(sj, 32);
            acc0[j] = sj;
        }
        if (g8 == 0 && act) {
            float dv = dinv[node];
            if (BN) {
                half8_t h;
#pragma unroll
                for (int j = 0; j < 8; ++j) {
                    float o = dv * acc0[j] + bias[j];
                    o = fmaxf(o * sf[j] + tf[j], 0.0f);
                    h[j] = (_Float16)o;
                }
                ((half8_t*)outv)[(size_t)node * NS + s] = h;  // y compact N x 64
            } else {
                float o[8];
#pragma unroll
                for (int j = 0; j < 8; ++j) o[j] = dv * acc0[j] + bias[j];
                float* op = (float*)outv + (size_t)node * FOUT + 8 * s;
                *(float4*)op = make_float4(o[0], o[1], o[2], o[3]);
                *(float4*)(op + 4) = make_float4(o[4], o[5], o[6], o[7]);
            }
        }
    }
}

// ================= launch =================

extern "C" void kernel_launch(void* const* d_in, const int* in_sizes, int n_in,
                              void* d_out, int out_size, void* d_ws, size_t ws_size,
                              hipStream_t stream) {
    const float* x   = (const float*)d_in[0];
    const int*   ei  = (const int*)d_in[1];
    const float* W1  = (const float*)d_in[2];
    const float* b1  = (const float*)d_in[3];
    const float* g1  = (const float*)d_in[4];
    const float* be1 = (const float*)d_in[5];
    const float* m1  = (const float*)d_in[6];
    const float* v1  = (const float*)d_in[7];
    const float* W2  = (const float*)d_in[8];
    const float* b2  = (const float*)d_in[9];
    const float* g2  = (const float*)d_in[10];
    const float* be2 = (const float*)d_in[11];
    const float* m2  = (const float*)d_in[12];
    const float* v2  = (const float*)d_in[13];
    const float* W3  = (const float*)d_in[14];
    const float* b3  = (const float*)d_in[15];

    const int FIN = 128, H = 64;
    int N = in_sizes[0] / FIN;       // 50000
    int E = in_sizes[1] / 2;         // 1600000
    const int* src = ei;
    const int* dst = ei + E;
    int B = (N + 255) >> 8;          // 196 buckets

    char* ws = (char*)d_ws;
    size_t off = 0;
    auto carve = [&](size_t bytes) -> void* {
        void* p = ws + off;
        off += (bytes + 255) & ~(size_t)255;
        return p;
    };
    float*  dinv    = (float*)carve((size_t)N * 4);
    int*    row_ptr = (int*)carve((size_t)N * 4);
    unsigned short* len = (unsigned short*)carve((size_t)N * 2);
    unsigned short* col = (unsigned short*)carve((size_t)B * SLOT * 2);
    unsigned int*   ebuf = (unsigned int*)carve((size_t)B * SLOT * 4);
    half2_t* hs     = (half2_t*)carve((size_t)N * 64 * 2);  // padded 128B rows
    _Float16* y     = (_Float16*)carve((size_t)N * 64 * 2);
    int*    bcur    = (int*)carve(512 * 4);
    (void)ws_size; (void)n_in; (void)out_size;

    int eb2k = (E + 2047) / 2048;

    k_init<<<1, 256, 0, stream>>>(bcur, B);
    k_bscatter<<<eb2k, 256, 0, stream>>>(src, dst, bcur, ebuf, E, B);
    k_bfinal<<<B, 256, 0, stream>>>(ebuf, bcur, row_ptr, len, dinv, col, N);

    int gb = (N + 63) / 64;
    const half8_t* hs8 = (const half8_t*)hs;
    // layer 1
    k_gemm_scale<128, 64, false><<<gb, 256, 0, stream>>>(x, W1, dinv, hs, N);
    k_agg<64, true><<<4096, 256, 0, stream>>>(hs8, col, row_ptr, len, dinv,
                                              b1, g1, be1, m1, v1, y, N);
    // layer 2
    k_gemm_scale<64, 64, true><<<gb, 256, 0, stream>>>(y, W2, dinv, hs, N);
    k_agg<64, true><<<4096, 256, 0, stream>>>(hs8, col, row_ptr, len, dinv,
                                              b2, g2, be2, m2, v2, y, N);
    // layer 3: 40 features in padded 128B rows
    k_gemm_scale<64, 40, true><<<gb, 256, 0, stream>>>(y, W3, dinv, hs, N);
    k_agg<40, false><<<4096, 256, 0, stream>>>(hs8, col, row_ptr, len, dinv,
                                               b3, nullptr, nullptr, nullptr, nullptr,
                                               d_out, N);
}